// Round 4
// baseline (377.089 us; speedup 1.0000x reference)
//
#include <hip/hip_runtime.h>
#include <hip/hip_fp16.h>

#define N_NODES 100000
#define N_EDGES 1600000
#define IN_F 128
#define HID_F 64
#define CLS_F 32

#define NBKT 512                 // buckets of 196 dst nodes each
#define BKT_NODES 196
#define NBLK 800                 // edge partition blocks (3.1 blocks/CU)
#define EPB 2000                 // edges per partition block (800*2000 = 1.6M exact)
#define NVAL (NBKT * NBLK)       // 409600 = 1024*400 (exact fit for scan)
#define SCH 100                  // int4 chunks per scan thread (NVAL/1024/4)
#define CAPB 5120                // fixed padded csr region per bucket (mean ~3900, >16 sigma)

typedef short s8v __attribute__((ext_vector_type(8)));
typedef float f4v __attribute__((ext_vector_type(4)));
typedef _Float16 h2v __attribute__((ext_vector_type(2)));

__device__ __forceinline__ unsigned short f2h(float f) {
    return __half_as_ushort(__float2half_rn(f));
}
__device__ __forceinline__ int packh2(float x, float y) {
    __half2 p = __floats2half2_rn(x, y);
    union { __half2 h; int i; } c; c.h = p; return c.i;
}

// accumulate 8 fp16 feats (int4) into 8 f32 accumulators, 1 instr/feat
__device__ __forceinline__ void dot8(float* a, int4 v) {
#if __has_builtin(__builtin_amdgcn_fdot2)
    union { int4 i; h2v h[4]; } c; c.i = v;
    const h2v E0 = {(_Float16)1.f, (_Float16)0.f};
    const h2v E1 = {(_Float16)0.f, (_Float16)1.f};
#pragma unroll
    for (int j = 0; j < 4; j++) {
        a[2 * j]     = __builtin_amdgcn_fdot2(c.h[j], E0, a[2 * j], false);
        a[2 * j + 1] = __builtin_amdgcn_fdot2(c.h[j], E1, a[2 * j + 1], false);
    }
#else
    union { int4 i; __half2 h[4]; } c; c.i = v;
#pragma unroll
    for (int j = 0; j < 4; j++) {
        float2 f = __half22float2(c.h[j]);
        a[2 * j] += f.x; a[2 * j + 1] += f.y;
    }
#endif
}
__device__ __forceinline__ void dot4(float* a, int2 v) {
#if __has_builtin(__builtin_amdgcn_fdot2)
    union { int2 i; h2v h[2]; } c; c.i = v;
    const h2v E0 = {(_Float16)1.f, (_Float16)0.f};
    const h2v E1 = {(_Float16)0.f, (_Float16)1.f};
#pragma unroll
    for (int j = 0; j < 2; j++) {
        a[2 * j]     = __builtin_amdgcn_fdot2(c.h[j], E0, a[2 * j], false);
        a[2 * j + 1] = __builtin_amdgcn_fdot2(c.h[j], E1, a[2 * j + 1], false);
    }
#else
    union { int2 i; __half2 h[2]; } c; c.i = v;
#pragma unroll
    for (int j = 0; j < 2; j++) {
        float2 f = __half22float2(c.h[j]);
        a[2 * j] += f.x; a[2 * j + 1] += f.y;
    }
#endif
}

// ---------------------------------------------------------------------------
// CSR build: bucket histogram -> scan -> scatter -> per-bucket counting sort.
// Node segments padded to multiple of 8 with dummy index N_NODES (zero rows).
// ---------------------------------------------------------------------------

__global__ __launch_bounds__(256) void bucketA_kernel(const int* __restrict__ dst,
                                                      int* __restrict__ bh) {
    __shared__ int h[NBKT];
    for (int i = threadIdx.x; i < NBKT; i += 256) h[i] = 0;
    __syncthreads();
    int e0 = blockIdx.x * EPB;
    int e1 = min(e0 + EPB, N_EDGES);
    for (int e = e0 + threadIdx.x; e < e1; e += 256)
        atomicAdd(&h[dst[e] / BKT_NODES], 1);
    __syncthreads();
    for (int i = threadIdx.x; i < NBKT; i += 256)
        bh[i * NBLK + blockIdx.x] = h[i];
}

// NVAL = 409600: streaming two-pass scan. Pass 1: per-thread sum of 100 int4
// (no register residency). Butterfly-scan totals. Pass 2: re-read (L2-hot)
// and write running exclusive prefix in place.
__global__ __launch_bounds__(1024) void scan_hist_kernel(int* __restrict__ bh) {
    __shared__ int wsum[16];
    int t = threadIdx.x;
    const int4* p = (const int4*)bh + (size_t)t * SCH;
    int local = 0;
#pragma unroll 10
    for (int i = 0; i < SCH; i++) {
        int4 v = p[i];
        local += v.x + v.y + v.z + v.w;
    }
    int lane = t & 63, wd = t >> 6;
    int s = local;
#pragma unroll
    for (int d = 1; d < 64; d <<= 1) {
        int u = __shfl_up(s, d);
        if (lane >= d) s += u;
    }
    if (lane == 63) wsum[wd] = s;
    __syncthreads();
    int wbase = 0;
    for (int i = 0; i < wd; i++) wbase += wsum[i];
    int run = wbase + s - local;         // exclusive base for this thread
    int4* q = (int4*)bh + (size_t)t * SCH;
#pragma unroll 10
    for (int i = 0; i < SCH; i++) {
        int4 v = p[i];
        int e0 = run;
        int e1 = e0 + v.x;
        int e2 = e1 + v.y;
        int e3 = e2 + v.z;
        run = e3 + v.w;
        q[i] = make_int4(e0, e1, e2, e3);
    }
}

__global__ __launch_bounds__(256) void bucketB_kernel(const int* __restrict__ src,
                                                      const int* __restrict__ dst,
                                                      const int* __restrict__ bhScan,
                                                      unsigned* __restrict__ bkt) {
    __shared__ int cur[NBKT];
    for (int i = threadIdx.x; i < NBKT; i += 256)
        cur[i] = bhScan[i * NBLK + blockIdx.x];
    __syncthreads();
    int e0 = blockIdx.x * EPB;
    int e1 = min(e0 + EPB, N_EDGES);
    for (int e = e0 + threadIdx.x; e < e1; e += 256) {
        int d = dst[e];
        int g = d / BKT_NODES;
        unsigned pk = ((unsigned)(d - g * BKT_NODES) << 17) | (unsigned)src[e];
        int pos = atomicAdd(&cur[g], 1);
        bkt[pos] = pk;
    }
}

__global__ __launch_bounds__(256) void sort_bucket_kernel(const int* __restrict__ bhScan,
                                                          const unsigned* __restrict__ bkt,
                                                          int* __restrict__ csr,
                                                          int* __restrict__ off,
                                                          int* __restrict__ endp,
                                                          float* __restrict__ dinv) {
    __shared__ int hist[BKT_NODES];
    __shared__ int loff[BKT_NODES];    // mutated by scatter atomics
    __shared__ int loffB[BKT_NODES];   // stable padded bases
    __shared__ int wt[4];
    __shared__ int csrS[CAPB];
    int b = blockIdx.x;
    int t = threadIdx.x;
    int s0 = bhScan[b * NBLK];
    int s1 = (b < NBKT - 1) ? bhScan[(b + 1) * NBLK] : N_EDGES;
    int nE = s1 - s0;

    for (int i = t; i < BKT_NODES; i += 256) hist[i] = 0;
    __syncthreads();
    for (int i = t; i < nE; i += 256)
        atomicAdd(&hist[bkt[s0 + i] >> 17], 1);
    __syncthreads();

    // exclusive scan of PADDED per-node sizes (pad to multiple of 8)
    int h0 = 0, h1 = 0;
    if (t < 98) { h0 = hist[2 * t]; h1 = hist[2 * t + 1]; }
    int p0 = (h0 + 7) & ~7;
    int p1 = (h1 + 7) & ~7;
    int sum = p0 + p1;
    int lane = t & 63, w = t >> 6;
    int s = sum;
#pragma unroll
    for (int d = 1; d < 64; d <<= 1) {
        int u = __shfl_up(s, d);
        if (lane >= d) s += u;
    }
    if (lane == 63) wt[w] = s;
    __syncthreads();
    int wbase = 0;
    for (int i = 0; i < w; i++) wbase += wt[i];
    int excl = wbase + s - sum;
    if (t < 98) {
        loff[2 * t] = excl;         loffB[2 * t] = excl;
        loff[2 * t + 1] = excl + p0; loffB[2 * t + 1] = excl + p0;
    }
    __syncthreads();

    for (int j = t; j < BKT_NODES; j += 256) {
        int n = b * BKT_NODES + j;
        if (n < N_NODES) {
            int c = hist[j];
            int o = b * CAPB + loff[j];
            off[n] = o;
            endp[n] = o + ((c + 7) & ~7);          // padded length
            dinv[n] = rsqrtf((float)(c + 1));
        }
    }
    __syncthreads();

    // scatter into padded staging
    for (int i = t; i < nE; i += 256) {
        unsigned pk = bkt[s0 + i];
        int dl = (int)(pk >> 17);
        int p = atomicAdd(&loff[dl], 1);
        csrS[p] = (int)(pk & 0x1FFFFu);
    }
    __syncthreads();

    // fill pad slots with dummy node id (zero feature row)
    for (int j = t; j < BKT_NODES; j += 256) {
        int c = hist[j];
        int bse = loffB[j];
        int pe = bse + ((c + 7) & ~7);
        for (int p = bse + c; p < pe; p++) csrS[p] = N_NODES;
    }
    __syncthreads();

    int padTot = wt[0] + wt[1] + wt[2] + wt[3];
    for (int i = t; i < padTot; i += 256) csr[b * CAPB + i] = csrS[i];
}

// ---------------------------------------------------------------------------
// layer 1 GEMM via MFMA f16. y1 = (x @ W1) * dinv, fp16 rows of 128 B;
// row N_NODES written as zeros (dummy target for csr padding).
// ---------------------------------------------------------------------------
#define XBM 64
__global__ __launch_bounds__(256) void xw1_kernel(const float* __restrict__ x,
                                                  const float* __restrict__ W1,
                                                  const float* __restrict__ dinv,
                                                  unsigned short* __restrict__ y1h) {
    __shared__ __align__(16) unsigned short Wb[16 * 64 * 8];   // 16 KB, B-frag packed
    __shared__ __align__(16) unsigned short xb[XBM][IN_F + 8]; // 17 KB

    int tid = threadIdx.x;

    for (int i = tid; i < IN_F * HID_F; i += 256) {
        int k = i >> 6, n = i & 63;
        int kc = k >> 5, kw = k & 31;
        int nt = n >> 4, nl = n & 15;
        int quad = kw >> 3, j = kw & 7;
        Wb[(((kc * 4 + nt) * 64) + quad * 16 + nl) * 8 + j] = f2h(W1[i]);
    }

    int nodeBase = blockIdx.x * XBM;
    {
        int snl = tid >> 2;
        int sk0 = (tid & 3) * 32;
        int n = nodeBase + snl;
#pragma unroll
        for (int kk = 0; kk < 32; kk += 4) {
            float4 v = make_float4(0.f, 0.f, 0.f, 0.f);
            if (n < N_NODES) v = *(const float4*)(x + (size_t)n * IN_F + sk0 + kk);
            ushort4 o;
            o.x = f2h(v.x); o.y = f2h(v.y); o.z = f2h(v.z); o.w = f2h(v.w);
            *(ushort4*)(&xb[snl][sk0 + kk]) = o;
        }
    }
    __syncthreads();

    int wave = tid >> 6, lane = tid & 63;
    int quad = lane >> 4, l15 = lane & 15;
    int rowBase = wave * 16;

    f4v acc[4];
#pragma unroll
    for (int i = 0; i < 4; i++) acc[i] = (f4v){0.f, 0.f, 0.f, 0.f};

#pragma unroll
    for (int kc = 0; kc < 4; kc++) {
        s8v a = *(const s8v*)(&xb[rowBase + l15][kc * 32 + quad * 8]);
#pragma unroll
        for (int nt = 0; nt < 4; nt++) {
            s8v b = *(const s8v*)(&Wb[((kc * 4 + nt) * 64 + lane) * 8]);
            acc[nt] = __builtin_amdgcn_mfma_f32_16x16x32_f16(a, b, acc[nt], 0, 0, 0);
        }
    }

    float dv[4];
    int n0 = nodeBase + rowBase + quad * 4;
#pragma unroll
    for (int r = 0; r < 4; r++)
        dv[r] = (n0 + r < N_NODES) ? dinv[n0 + r] : 0.f;
#pragma unroll
    for (int nt = 0; nt < 4; nt++) {
#pragma unroll
        for (int r = 0; r < 4; r++) {
            int n = n0 + r;
            if (n < N_NODES + 1)    // row N_NODES written as zeros (dv=0)
                y1h[(size_t)n * HID_F + nt * 16 + l15] = f2h(acc[nt][r] * dv[r]);
        }
    }
}

// ---------------------------------------------------------------------------
// gather1 v5: 2 nodes/wave, 8 lanes/edge (dwordx4 = full 128B rows, 8 edges
// per wave-wide load). fdot2 accumulate (1 instr/feat, exact f32). 2-deep
// software pipeline: indices prefetched 1 iter ahead, rows 1 iter ahead.
// Loop runs to lmax with dummy-index clamp (dummy row is L1-hot zeros) -> no
// divergent tails. Merged A/B butterfly: xor-32 level cross-selects so lanes
// <32 reduce node A, lanes >=32 node B; epilogue runs once on selected node.
// Output h = relu(agg*dinv + b1) fp16; W2 deferred to y2_kernel (linearity).
// ---------------------------------------------------------------------------
__global__ __launch_bounds__(256) void gather1_kernel(
        const int* __restrict__ off, const int* __restrict__ endp,
        const int* __restrict__ csr, const unsigned short* __restrict__ y1h,
        const float* __restrict__ dinv, const float* __restrict__ b1,
        unsigned short* __restrict__ hout) {
    int tid = threadIdx.x;
    int wv = __builtin_amdgcn_readfirstlane(tid >> 6);
    int wave = blockIdx.x * 4 + wv;
    int nA = wave * 2, nB = nA + 1;
    int lane = tid & 63;
    int f = lane & 7;
    int g = lane >> 3;
    int fo = f * 16;

    int offA = off[nA], offB = off[nB];          // uniform -> s_load
    int lenA = endp[nA] - offA, lenB = endp[nB] - offB;   // multiples of 8
    int lmax = max(lenA, lenB);
    const int* pA = csr + offA + g;
    const int* pB = csr + offB + g;
    const char* yb = (const char*)y1h;

    float aA[8], aB[8];
#pragma unroll
    for (int j = 0; j < 8; j++) { aA[j] = 0.f; aB[j] = 0.f; }

    if (lmax > 0) {
        int rA = pA[0], rB = pB[0];
        int iA = (lenA > 0) ? rA : N_NODES;
        int iB = (lenB > 0) ? rB : N_NODES;
        int4 vA = *(const int4*)(yb + (size_t)iA * 128 + fo);
        int4 vB = *(const int4*)(yb + (size_t)iB * 128 + fo);
        int rA1 = pA[8], rB1 = pB[8];            // prefetch (csr has slack)
        for (int t = 8; t < lmax; t += 8) {
            int inA = (t < lenA) ? rA1 : N_NODES;
            int inB = (t < lenB) ? rB1 : N_NODES;
            int4 nxA = *(const int4*)(yb + (size_t)inA * 128 + fo);
            int4 nxB = *(const int4*)(yb + (size_t)inB * 128 + fo);
            rA1 = pA[t + 8]; rB1 = pB[t + 8];    // prefetch (slack-covered)
            dot8(aA, vA); dot8(aB, vB);
            vA = nxA; vB = nxB;
        }
        dot8(aA, vA); dot8(aB, vB);
    }

    // merged butterfly: level 32 cross-select, then 16, 8
    float c8[8];
#pragma unroll
    for (int j = 0; j < 8; j++) {
        float sel = (lane < 32) ? aB[j] : aA[j];
        float oth = __shfl_xor(sel, 32);
        c8[j] = ((lane < 32) ? aA[j] : aB[j]) + oth;
    }
#pragma unroll
    for (int m = 8; m <= 16; m <<= 1)
#pragma unroll
        for (int j = 0; j < 8; j++) c8[j] += __shfl_xor(c8[j], m);

    int node = (lane < 32) ? nA : nB;

    // self loop
    int4 sv = *(const int4*)(yb + (size_t)node * 128 + fo);
    dot8(c8, sv);

    float dvA = dinv[nA], dvB = dinv[nB];
    float dvS = (lane < 32) ? dvA : dvB;
    float4 bl = *(const float4*)(b1 + 8 * f);
    float4 bh4 = *(const float4*)(b1 + 8 * f + 4);
    float bb[8] = {bl.x, bl.y, bl.z, bl.w, bh4.x, bh4.y, bh4.z, bh4.w};
    float h[8];
#pragma unroll
    for (int j = 0; j < 8; j++)
        h[j] = fmaxf(fmaf(c8[j], dvS, bb[j]), 0.f);
    int4 H;
    H.x = packh2(h[0], h[1]); H.y = packh2(h[2], h[3]);
    H.z = packh2(h[4], h[5]); H.w = packh2(h[6], h[7]);
    if ((lane & 31) < 8)
        *(int4*)((char*)hout + (size_t)node * 128 + fo) = H;
}

// ---------------------------------------------------------------------------
// y2 = (h @ W2) * dinv via MFMA f16: 100K x 64 x 32. 64 nodes per block.
// Row N_NODES written as zeros (dummy target for gather2 padding).
// ---------------------------------------------------------------------------
#define YBM 64
__global__ __launch_bounds__(256) void y2_kernel(const unsigned short* __restrict__ h,
                                                 const float* __restrict__ W2,
                                                 const float* __restrict__ dinv,
                                                 unsigned short* __restrict__ y2h) {
    __shared__ __align__(16) unsigned short Wb[2 * 2 * 64 * 8];  // 4 KB
    __shared__ __align__(16) unsigned short hb[YBM][HID_F + 8];  // 9 KB
    int tid = threadIdx.x;

    for (int i = tid; i < HID_F * CLS_F; i += 256) {
        int k = i >> 5, n = i & 31;
        int kc = k >> 5, kw = k & 31;
        int nt = n >> 4, nl = n & 15;
        int quad = kw >> 3, j = kw & 7;
        Wb[(((kc * 2 + nt) * 64) + quad * 16 + nl) * 8 + j] = f2h(W2[i]);
    }

    int nodeBase = blockIdx.x * YBM;
    {
        int row = tid >> 2, sseg = tid & 3;
        int n = nodeBase + row;
        int4 v0 = {0, 0, 0, 0}, v1 = {0, 0, 0, 0};
        if (n < N_NODES) {
            const char* hp = (const char*)h + (size_t)n * 128 + sseg * 32;
            v0 = *(const int4*)hp;
            v1 = *(const int4*)(hp + 16);
        }
        *(int4*)(&hb[row][sseg * 16]) = v0;
        *(int4*)(&hb[row][sseg * 16 + 8]) = v1;
    }
    __syncthreads();

    int wave = tid >> 6, lane = tid & 63;
    int quad = lane >> 4, l15 = lane & 15;
    int rowBase = wave * 16;

    f4v acc[2];
#pragma unroll
    for (int i = 0; i < 2; i++) acc[i] = (f4v){0.f, 0.f, 0.f, 0.f};

#pragma unroll
    for (int kc = 0; kc < 2; kc++) {
        s8v a = *(const s8v*)(&hb[rowBase + l15][kc * 32 + quad * 8]);
#pragma unroll
        for (int nt = 0; nt < 2; nt++) {
            s8v b = *(const s8v*)(&Wb[((kc * 2 + nt) * 64 + lane) * 8]);
            acc[nt] = __builtin_amdgcn_mfma_f32_16x16x32_f16(a, b, acc[nt], 0, 0, 0);
        }
    }

    float dv[4];
    int n0 = nodeBase + rowBase + quad * 4;
#pragma unroll
    for (int r = 0; r < 4; r++)
        dv[r] = (n0 + r < N_NODES) ? dinv[n0 + r] : 0.f;
#pragma unroll
    for (int nt = 0; nt < 2; nt++) {
#pragma unroll
        for (int r = 0; r < 4; r++) {
            int n = n0 + r;
            if (n < N_NODES + 1)
                y2h[(size_t)n * CLS_F + nt * 16 + l15] = f2h(acc[nt][r] * dv[r]);
        }
    }
}

// ---------------------------------------------------------------------------
// gather2 v5: same structure as gather1 v5; rows are 64 B (32 fp16) ->
// dwordx2 per lane. out = (sum y2[nbr] + y2[self]) * dinv + b2, f32.
// ---------------------------------------------------------------------------
__global__ __launch_bounds__(256) void gather2_kernel(const int* __restrict__ off,
                                                      const int* __restrict__ endp,
                                                      const int* __restrict__ csr,
                                                      const unsigned short* __restrict__ y2h,
                                                      const float* __restrict__ dinv,
                                                      const float* __restrict__ b2,
                                                      float* __restrict__ out) {
    int tid = threadIdx.x;
    int wv = __builtin_amdgcn_readfirstlane(tid >> 6);
    int wave = blockIdx.x * 4 + wv;
    int nA = wave * 2, nB = nA + 1;
    int lane = tid & 63;
    int f = lane & 7;
    int g = lane >> 3;
    int fo = f * 8;

    int offA = off[nA], offB = off[nB];
    int lenA = endp[nA] - offA, lenB = endp[nB] - offB;
    int lmax = max(lenA, lenB);
    const int* pA = csr + offA + g;
    const int* pB = csr + offB + g;
    const char* yb = (const char*)y2h;

    float aA[4], aB[4];
#pragma unroll
    for (int j = 0; j < 4; j++) { aA[j] = 0.f; aB[j] = 0.f; }

    if (lmax > 0) {
        int rA = pA[0], rB = pB[0];
        int iA = (lenA > 0) ? rA : N_NODES;
        int iB = (lenB > 0) ? rB : N_NODES;
        int2 vA = *(const int2*)(yb + (size_t)iA * 64 + fo);
        int2 vB = *(const int2*)(yb + (size_t)iB * 64 + fo);
        int rA1 = pA[8], rB1 = pB[8];
        for (int t = 8; t < lmax; t += 8) {
            int inA = (t < lenA) ? rA1 : N_NODES;
            int inB = (t < lenB) ? rB1 : N_NODES;
            int2 nxA = *(const int2*)(yb + (size_t)inA * 64 + fo);
            int2 nxB = *(const int2*)(yb + (size_t)inB * 64 + fo);
            rA1 = pA[t + 8]; rB1 = pB[t + 8];
            dot4(aA, vA); dot4(aB, vB);
            vA = nxA; vB = nxB;
        }
        dot4(aA, vA); dot4(aB, vB);
    }

    float c4[4];
#pragma unroll
    for (int j = 0; j < 4; j++) {
        float sel = (lane < 32) ? aB[j] : aA[j];
        float oth = __shfl_xor(sel, 32);
        c4[j] = ((lane < 32) ? aA[j] : aB[j]) + oth;
    }
#pragma unroll
    for (int m = 8; m <= 16; m <<= 1)
#pragma unroll
        for (int j = 0; j < 4; j++) c4[j] += __shfl_xor(c4[j], m);

    int node = (lane < 32) ? nA : nB;

    int2 sv = *(const int2*)(yb + (size_t)node * 64 + fo);
    dot4(c4, sv);

    float dvA = dinv[nA], dvB = dinv[nB];
    float dvS = (lane < 32) ? dvA : dvB;
    float4 b2v = *(const float4*)(b2 + 4 * f);
    float bbv[4] = {b2v.x, b2v.y, b2v.z, b2v.w};
    float4 o4;
    float* op = (float*)&o4;
#pragma unroll
    for (int j = 0; j < 4; j++)
        op[j] = fmaf(c4[j], dvS, bbv[j]);
    if ((lane & 31) < 8)
        *(float4*)(out + (size_t)node * CLS_F + f * 4) = o4;
}

extern "C" void kernel_launch(void* const* d_in, const int* in_sizes, int n_in,
                              void* d_out, int out_size, void* d_ws, size_t ws_size,
                              hipStream_t stream) {
    const float* x  = (const float*)d_in[0];
    const int*   ei = (const int*)d_in[1];
    // d_in[2] = edge_attr, unused by GCNConv
    const float* W1 = (const float*)d_in[3];
    const float* b1 = (const float*)d_in[4];
    const float* W2 = (const float*)d_in[5];
    const float* b2 = (const float*)d_in[6];
    float* out = (float*)d_out;

    const int* src = ei;
    const int* dst = ei + N_EDGES;

    char* ws = (char*)d_ws;
    size_t npad = ((size_t)N_NODES * 4 + 255) / 256 * 256;
    float* dinv = (float*)ws;
    int*   off  = (int*)(ws + npad);
    int*   endp = (int*)(ws + 2 * npad);
    int*   bh   = (int*)(ws + 3 * npad);              // NVAL=409600 ints (1.6 MB)
    int*   csr  = (int*)(ws + 3 * npad + 1638400);    // (NBKT+1)*CAPB ints (+slack bucket)
    char*  rbase = (char*)csr + (size_t)(NBKT + 1) * CAPB * 4;
    unsigned* bkt = (unsigned*)rbase;                 // 6.4 MB, dead after sort_bucket
    unsigned short* y1h = (unsigned short*)rbase;     // (N+1)*64 fp16 = 12.8 MB, aliases bkt
    unsigned short* y2h = (unsigned short*)(rbase + (size_t)(N_NODES + 1) * HID_F * 2);  // 6.4 MB
    unsigned short* hbuf = (unsigned short*)((char*)y2h + (size_t)(N_NODES + 1) * CLS_F * 2); // 12.8 MB

    dim3 blk(256);
    bucketA_kernel  <<<dim3(NBLK), blk, 0, stream>>>(dst, bh);
    scan_hist_kernel<<<dim3(1), dim3(1024), 0, stream>>>(bh);
    bucketB_kernel  <<<dim3(NBLK), blk, 0, stream>>>(src, dst, bh, bkt);
    sort_bucket_kernel<<<dim3(NBKT), blk, 0, stream>>>(bh, bkt, csr, off, endp, dinv);
    xw1_kernel      <<<dim3((N_NODES + XBM - 1) / XBM), blk, 0, stream>>>(x, W1, dinv, y1h);
    gather1_kernel  <<<dim3(N_NODES / 8), blk, 0, stream>>>(off, endp, csr, y1h, dinv, b1, hbuf);
    y2_kernel       <<<dim3((N_NODES + YBM) / YBM), blk, 0, stream>>>(hbuf, W2, dinv, y2h);
    gather2_kernel  <<<dim3(N_NODES / 8), blk, 0, stream>>>(off, endp, csr, y2h, dinv, b2, out);
}

// Round 5
// 221.927 us; speedup vs baseline: 1.6992x; 1.6992x over previous
//
#include <hip/hip_runtime.h>
#include <hip/hip_fp16.h>

#define N_NODES 100000
#define N_EDGES 1600000
#define IN_F 128
#define HID_F 64
#define CLS_F 32

#define NBKT 512                 // buckets of 196 dst nodes each
#define BKT_NODES 196
#define NBLK 800                 // edge partition blocks (3.1 blocks/CU)
#define EPB 2000                 // edges per partition block (800*2000 = 1.6M exact)
#define CAPB_RAW 4096            // fixed raw staging region per bucket (mean 3136, +17 sigma)
#define CAPB 5120                // fixed padded csr region per bucket (mean ~3800, >20 sigma)

typedef short s8v __attribute__((ext_vector_type(8)));
typedef float f4v __attribute__((ext_vector_type(4)));
typedef _Float16 h2v __attribute__((ext_vector_type(2)));

__device__ __forceinline__ unsigned short f2h(float f) {
    return __half_as_ushort(__float2half_rn(f));
}
__device__ __forceinline__ int packh2(float x, float y) {
    __half2 p = __floats2half2_rn(x, y);
    union { __half2 h; int i; } c; c.h = p; return c.i;
}

// accumulate 8 fp16 feats (int4) into 8 f32 accumulators, 1 instr/feat
__device__ __forceinline__ void dot8(float* a, int4 v) {
#if __has_builtin(__builtin_amdgcn_fdot2)
    union { int4 i; h2v h[4]; } c; c.i = v;
    const h2v E0 = {(_Float16)1.f, (_Float16)0.f};
    const h2v E1 = {(_Float16)0.f, (_Float16)1.f};
#pragma unroll
    for (int j = 0; j < 4; j++) {
        a[2 * j]     = __builtin_amdgcn_fdot2(c.h[j], E0, a[2 * j], false);
        a[2 * j + 1] = __builtin_amdgcn_fdot2(c.h[j], E1, a[2 * j + 1], false);
    }
#else
    union { int4 i; __half2 h[4]; } c; c.i = v;
#pragma unroll
    for (int j = 0; j < 4; j++) {
        float2 f = __half22float2(c.h[j]);
        a[2 * j] += f.x; a[2 * j + 1] += f.y;
    }
#endif
}
__device__ __forceinline__ void dot4(float* a, int2 v) {
#if __has_builtin(__builtin_amdgcn_fdot2)
    union { int2 i; h2v h[2]; } c; c.i = v;
    const h2v E0 = {(_Float16)1.f, (_Float16)0.f};
    const h2v E1 = {(_Float16)0.f, (_Float16)1.f};
#pragma unroll
    for (int j = 0; j < 2; j++) {
        a[2 * j]     = __builtin_amdgcn_fdot2(c.h[j], E0, a[2 * j], false);
        a[2 * j + 1] = __builtin_amdgcn_fdot2(c.h[j], E1, a[2 * j + 1], false);
    }
#else
    union { int2 i; __half2 h[2]; } c; c.i = v;
#pragma unroll
    for (int j = 0; j < 2; j++) {
        float2 f = __half22float2(c.h[j]);
        a[2 * j] += f.x; a[2 * j + 1] += f.y;
    }
#endif
}

// ---------------------------------------------------------------------------
// CSR build v7 — no global scan. Staging buffer bkt has FIXED per-bucket
// regions (b*CAPB_RAW) with device cursors; one fused scatter kernel does
// LDS histogram -> one global atomicAdd per touched bucket (range reserve)
// -> LDS-cursor scatter. Order within a bucket is nondeterministic, which
// is fine: sort_bucket re-sorts by dst-local, and per-node src order does
// not affect a sum.
// ---------------------------------------------------------------------------

__global__ __launch_bounds__(256) void init_cursor_kernel(int* __restrict__ cursor) {
    int t = blockIdx.x * 256 + threadIdx.x;
    if (t < NBKT) cursor[t] = t * CAPB_RAW;
}

__global__ __launch_bounds__(256) void bucket_scatter_kernel(
        const int* __restrict__ src, const int* __restrict__ dst,
        int* __restrict__ cursor, unsigned* __restrict__ bkt) {
    __shared__ int h[NBKT];
    __shared__ int base[NBKT];
    __shared__ int lcur[NBKT];
    __shared__ unsigned pkS[EPB];
    __shared__ short gS[EPB];
    int t = threadIdx.x;
    for (int i = t; i < NBKT; i += 256) { h[i] = 0; lcur[i] = 0; }
    __syncthreads();

    int e0 = blockIdx.x * EPB;
    for (int i = t; i < EPB; i += 256) {
        int e = e0 + i;
        int d = dst[e];
        int g = d / BKT_NODES;
        pkS[i] = ((unsigned)(d - g * BKT_NODES) << 17) | (unsigned)src[e];
        gS[i] = (short)g;
        atomicAdd(&h[g], 1);
    }
    __syncthreads();

    for (int g = t; g < NBKT; g += 256)
        if (h[g] > 0) base[g] = atomicAdd(&cursor[g], h[g]);
    __syncthreads();

    for (int i = t; i < EPB; i += 256) {
        int g = gS[i];
        int p = base[g] + atomicAdd(&lcur[g], 1);
        bkt[p] = pkS[i];
    }
}

__global__ __launch_bounds__(256) void sort_bucket_kernel(const int* __restrict__ cursor,
                                                          const unsigned* __restrict__ bkt,
                                                          int* __restrict__ csr,
                                                          int* __restrict__ off,
                                                          int* __restrict__ endp,
                                                          float* __restrict__ dinv) {
    __shared__ int hist[BKT_NODES];
    __shared__ int loff[BKT_NODES];    // mutated by scatter atomics
    __shared__ int loffB[BKT_NODES];   // stable padded bases
    __shared__ int wt[4];
    __shared__ int csrS[CAPB];
    int b = blockIdx.x;
    int t = threadIdx.x;
    int s0 = b * CAPB_RAW;
    int nE = cursor[b] - s0;           // raw bucket size

    for (int i = t; i < BKT_NODES; i += 256) hist[i] = 0;
    __syncthreads();
    for (int i = t; i < nE; i += 256)
        atomicAdd(&hist[bkt[s0 + i] >> 17], 1);
    __syncthreads();

    // exclusive scan of PADDED per-node sizes (pad to multiple of 8)
    int h0 = 0, h1 = 0;
    if (t < 98) { h0 = hist[2 * t]; h1 = hist[2 * t + 1]; }
    int p0 = (h0 + 7) & ~7;
    int p1 = (h1 + 7) & ~7;
    int sum = p0 + p1;
    int lane = t & 63, w = t >> 6;
    int s = sum;
#pragma unroll
    for (int d = 1; d < 64; d <<= 1) {
        int u = __shfl_up(s, d);
        if (lane >= d) s += u;
    }
    if (lane == 63) wt[w] = s;
    __syncthreads();
    int wbase = 0;
    for (int i = 0; i < w; i++) wbase += wt[i];
    int excl = wbase + s - sum;
    if (t < 98) {
        loff[2 * t] = excl;         loffB[2 * t] = excl;
        loff[2 * t + 1] = excl + p0; loffB[2 * t + 1] = excl + p0;
    }
    __syncthreads();

    for (int j = t; j < BKT_NODES; j += 256) {
        int n = b * BKT_NODES + j;
        if (n < N_NODES) {
            int c = hist[j];
            int o = b * CAPB + loff[j];
            off[n] = o;
            endp[n] = o + ((c + 7) & ~7);          // padded length
            dinv[n] = rsqrtf((float)(c + 1));
        }
    }
    __syncthreads();

    // scatter into padded staging
    for (int i = t; i < nE; i += 256) {
        unsigned pk = bkt[s0 + i];
        int dl = (int)(pk >> 17);
        int p = atomicAdd(&loff[dl], 1);
        csrS[p] = (int)(pk & 0x1FFFFu);
    }
    __syncthreads();

    // fill pad slots with dummy node id (zero feature row)
    for (int j = t; j < BKT_NODES; j += 256) {
        int c = hist[j];
        int bse = loffB[j];
        int pe = bse + ((c + 7) & ~7);
        for (int p = bse + c; p < pe; p++) csrS[p] = N_NODES;
    }
    __syncthreads();

    int padTot = wt[0] + wt[1] + wt[2] + wt[3];
    for (int i = t; i < padTot; i += 256) csr[b * CAPB + i] = csrS[i];
}

// ---------------------------------------------------------------------------
// layer 1 GEMM via MFMA f16. y1 = (x @ W1) * dinv, fp16 rows of 128 B;
// row N_NODES written as zeros (dummy target for csr padding).
// ---------------------------------------------------------------------------
#define XBM 64
__global__ __launch_bounds__(256) void xw1_kernel(const float* __restrict__ x,
                                                  const float* __restrict__ W1,
                                                  const float* __restrict__ dinv,
                                                  unsigned short* __restrict__ y1h) {
    __shared__ __align__(16) unsigned short Wb[16 * 64 * 8];   // 16 KB, B-frag packed
    __shared__ __align__(16) unsigned short xb[XBM][IN_F + 8]; // 17 KB

    int tid = threadIdx.x;

    for (int i = tid; i < IN_F * HID_F; i += 256) {
        int k = i >> 6, n = i & 63;
        int kc = k >> 5, kw = k & 31;
        int nt = n >> 4, nl = n & 15;
        int quad = kw >> 3, j = kw & 7;
        Wb[(((kc * 4 + nt) * 64) + quad * 16 + nl) * 8 + j] = f2h(W1[i]);
    }

    int nodeBase = blockIdx.x * XBM;
    {
        int snl = tid >> 2;
        int sk0 = (tid & 3) * 32;
        int n = nodeBase + snl;
#pragma unroll
        for (int kk = 0; kk < 32; kk += 4) {
            float4 v = make_float4(0.f, 0.f, 0.f, 0.f);
            if (n < N_NODES) v = *(const float4*)(x + (size_t)n * IN_F + sk0 + kk);
            ushort4 o;
            o.x = f2h(v.x); o.y = f2h(v.y); o.z = f2h(v.z); o.w = f2h(v.w);
            *(ushort4*)(&xb[snl][sk0 + kk]) = o;
        }
    }
    __syncthreads();

    int wave = tid >> 6, lane = tid & 63;
    int quad = lane >> 4, l15 = lane & 15;
    int rowBase = wave * 16;

    f4v acc[4];
#pragma unroll
    for (int i = 0; i < 4; i++) acc[i] = (f4v){0.f, 0.f, 0.f, 0.f};

#pragma unroll
    for (int kc = 0; kc < 4; kc++) {
        s8v a = *(const s8v*)(&xb[rowBase + l15][kc * 32 + quad * 8]);
#pragma unroll
        for (int nt = 0; nt < 4; nt++) {
            s8v b = *(const s8v*)(&Wb[((kc * 4 + nt) * 64 + lane) * 8]);
            acc[nt] = __builtin_amdgcn_mfma_f32_16x16x32_f16(a, b, acc[nt], 0, 0, 0);
        }
    }

    float dv[4];
    int n0 = nodeBase + rowBase + quad * 4;
#pragma unroll
    for (int r = 0; r < 4; r++)
        dv[r] = (n0 + r < N_NODES) ? dinv[n0 + r] : 0.f;
#pragma unroll
    for (int nt = 0; nt < 4; nt++) {
#pragma unroll
        for (int r = 0; r < 4; r++) {
            int n = n0 + r;
            if (n < N_NODES + 1)    // row N_NODES written as zeros (dv=0)
                y1h[(size_t)n * HID_F + nt * 16 + l15] = f2h(acc[nt][r] * dv[r]);
        }
    }
}

// ---------------------------------------------------------------------------
// gather1 v5: 2 nodes/wave, 8 lanes/edge (dwordx4 = full 128B rows, 8 edges
// per wave-wide load). fdot2 accumulate (1 instr/feat, exact f32). 2-deep
// software pipeline. Merged A/B butterfly; epilogue once per selected node.
// Output h = relu(agg*dinv + b1) fp16; W2 deferred to y2_kernel (linearity).
// ---------------------------------------------------------------------------
__global__ __launch_bounds__(256) void gather1_kernel(
        const int* __restrict__ off, const int* __restrict__ endp,
        const int* __restrict__ csr, const unsigned short* __restrict__ y1h,
        const float* __restrict__ dinv, const float* __restrict__ b1,
        unsigned short* __restrict__ hout) {
    int tid = threadIdx.x;
    int wv = __builtin_amdgcn_readfirstlane(tid >> 6);
    int wave = blockIdx.x * 4 + wv;
    int nA = wave * 2, nB = nA + 1;
    int lane = tid & 63;
    int f = lane & 7;
    int g = lane >> 3;
    int fo = f * 16;

    int offA = off[nA], offB = off[nB];          // uniform -> s_load
    int lenA = endp[nA] - offA, lenB = endp[nB] - offB;   // multiples of 8
    int lmax = max(lenA, lenB);
    const int* pA = csr + offA + g;
    const int* pB = csr + offB + g;
    const char* yb = (const char*)y1h;

    float aA[8], aB[8];
#pragma unroll
    for (int j = 0; j < 8; j++) { aA[j] = 0.f; aB[j] = 0.f; }

    if (lmax > 0) {
        int rA = pA[0], rB = pB[0];
        int iA = (lenA > 0) ? rA : N_NODES;
        int iB = (lenB > 0) ? rB : N_NODES;
        int4 vA = *(const int4*)(yb + (size_t)iA * 128 + fo);
        int4 vB = *(const int4*)(yb + (size_t)iB * 128 + fo);
        int rA1 = pA[8], rB1 = pB[8];            // prefetch (csr has slack)
        for (int t = 8; t < lmax; t += 8) {
            int inA = (t < lenA) ? rA1 : N_NODES;
            int inB = (t < lenB) ? rB1 : N_NODES;
            int4 nxA = *(const int4*)(yb + (size_t)inA * 128 + fo);
            int4 nxB = *(const int4*)(yb + (size_t)inB * 128 + fo);
            rA1 = pA[t + 8]; rB1 = pB[t + 8];    // prefetch (slack-covered)
            dot8(aA, vA); dot8(aB, vB);
            vA = nxA; vB = nxB;
        }
        dot8(aA, vA); dot8(aB, vB);
    }

    // merged butterfly: level 32 cross-select, then 16, 8
    float c8[8];
#pragma unroll
    for (int j = 0; j < 8; j++) {
        float sel = (lane < 32) ? aB[j] : aA[j];
        float oth = __shfl_xor(sel, 32);
        c8[j] = ((lane < 32) ? aA[j] : aB[j]) + oth;
    }
#pragma unroll
    for (int m = 8; m <= 16; m <<= 1)
#pragma unroll
        for (int j = 0; j < 8; j++) c8[j] += __shfl_xor(c8[j], m);

    int node = (lane < 32) ? nA : nB;

    // self loop
    int4 sv = *(const int4*)(yb + (size_t)node * 128 + fo);
    dot8(c8, sv);

    float dvA = dinv[nA], dvB = dinv[nB];
    float dvS = (lane < 32) ? dvA : dvB;
    float4 bl = *(const float4*)(b1 + 8 * f);
    float4 bh4 = *(const float4*)(b1 + 8 * f + 4);
    float bb[8] = {bl.x, bl.y, bl.z, bl.w, bh4.x, bh4.y, bh4.z, bh4.w};
    float h[8];
#pragma unroll
    for (int j = 0; j < 8; j++)
        h[j] = fmaxf(fmaf(c8[j], dvS, bb[j]), 0.f);
    int4 H;
    H.x = packh2(h[0], h[1]); H.y = packh2(h[2], h[3]);
    H.z = packh2(h[4], h[5]); H.w = packh2(h[6], h[7]);
    if ((lane & 31) < 8)
        *(int4*)((char*)hout + (size_t)node * 128 + fo) = H;
}

// ---------------------------------------------------------------------------
// y2 = (h @ W2) * dinv via MFMA f16: 100K x 64 x 32. 64 nodes per block.
// Row N_NODES written as zeros (dummy target for gather2 padding).
// ---------------------------------------------------------------------------
#define YBM 64
__global__ __launch_bounds__(256) void y2_kernel(const unsigned short* __restrict__ h,
                                                 const float* __restrict__ W2,
                                                 const float* __restrict__ dinv,
                                                 unsigned short* __restrict__ y2h) {
    __shared__ __align__(16) unsigned short Wb[2 * 2 * 64 * 8];  // 4 KB
    __shared__ __align__(16) unsigned short hb[YBM][HID_F + 8];  // 9 KB
    int tid = threadIdx.x;

    for (int i = tid; i < HID_F * CLS_F; i += 256) {
        int k = i >> 5, n = i & 31;
        int kc = k >> 5, kw = k & 31;
        int nt = n >> 4, nl = n & 15;
        int quad = kw >> 3, j = kw & 7;
        Wb[(((kc * 2 + nt) * 64) + quad * 16 + nl) * 8 + j] = f2h(W2[i]);
    }

    int nodeBase = blockIdx.x * YBM;
    {
        int row = tid >> 2, sseg = tid & 3;
        int n = nodeBase + row;
        int4 v0 = {0, 0, 0, 0}, v1 = {0, 0, 0, 0};
        if (n < N_NODES) {
            const char* hp = (const char*)h + (size_t)n * 128 + sseg * 32;
            v0 = *(const int4*)hp;
            v1 = *(const int4*)(hp + 16);
        }
        *(int4*)(&hb[row][sseg * 16]) = v0;
        *(int4*)(&hb[row][sseg * 16 + 8]) = v1;
    }
    __syncthreads();

    int wave = tid >> 6, lane = tid & 63;
    int quad = lane >> 4, l15 = lane & 15;
    int rowBase = wave * 16;

    f4v acc[2];
#pragma unroll
    for (int i = 0; i < 2; i++) acc[i] = (f4v){0.f, 0.f, 0.f, 0.f};

#pragma unroll
    for (int kc = 0; kc < 2; kc++) {
        s8v a = *(const s8v*)(&hb[rowBase + l15][kc * 32 + quad * 8]);
#pragma unroll
        for (int nt = 0; nt < 2; nt++) {
            s8v b = *(const s8v*)(&Wb[((kc * 2 + nt) * 64 + lane) * 8]);
            acc[nt] = __builtin_amdgcn_mfma_f32_16x16x32_f16(a, b, acc[nt], 0, 0, 0);
        }
    }

    float dv[4];
    int n0 = nodeBase + rowBase + quad * 4;
#pragma unroll
    for (int r = 0; r < 4; r++)
        dv[r] = (n0 + r < N_NODES) ? dinv[n0 + r] : 0.f;
#pragma unroll
    for (int nt = 0; nt < 2; nt++) {
#pragma unroll
        for (int r = 0; r < 4; r++) {
            int n = n0 + r;
            if (n < N_NODES + 1)
                y2h[(size_t)n * CLS_F + nt * 16 + l15] = f2h(acc[nt][r] * dv[r]);
        }
    }
}

// ---------------------------------------------------------------------------
// gather2 v5: same structure as gather1 v5; rows are 64 B (32 fp16) ->
// dwordx2 per lane. out = (sum y2[nbr] + y2[self]) * dinv + b2, f32.
// ---------------------------------------------------------------------------
__global__ __launch_bounds__(256) void gather2_kernel(const int* __restrict__ off,
                                                      const int* __restrict__ endp,
                                                      const int* __restrict__ csr,
                                                      const unsigned short* __restrict__ y2h,
                                                      const float* __restrict__ dinv,
                                                      const float* __restrict__ b2,
                                                      float* __restrict__ out) {
    int tid = threadIdx.x;
    int wv = __builtin_amdgcn_readfirstlane(tid >> 6);
    int wave = blockIdx.x * 4 + wv;
    int nA = wave * 2, nB = nA + 1;
    int lane = tid & 63;
    int f = lane & 7;
    int g = lane >> 3;
    int fo = f * 8;

    int offA = off[nA], offB = off[nB];
    int lenA = endp[nA] - offA, lenB = endp[nB] - offB;
    int lmax = max(lenA, lenB);
    const int* pA = csr + offA + g;
    const int* pB = csr + offB + g;
    const char* yb = (const char*)y2h;

    float aA[4], aB[4];
#pragma unroll
    for (int j = 0; j < 4; j++) { aA[j] = 0.f; aB[j] = 0.f; }

    if (lmax > 0) {
        int rA = pA[0], rB = pB[0];
        int iA = (lenA > 0) ? rA : N_NODES;
        int iB = (lenB > 0) ? rB : N_NODES;
        int2 vA = *(const int2*)(yb + (size_t)iA * 64 + fo);
        int2 vB = *(const int2*)(yb + (size_t)iB * 64 + fo);
        int rA1 = pA[8], rB1 = pB[8];
        for (int t = 8; t < lmax; t += 8) {
            int inA = (t < lenA) ? rA1 : N_NODES;
            int inB = (t < lenB) ? rB1 : N_NODES;
            int2 nxA = *(const int2*)(yb + (size_t)inA * 64 + fo);
            int2 nxB = *(const int2*)(yb + (size_t)inB * 64 + fo);
            rA1 = pA[t + 8]; rB1 = pB[t + 8];
            dot4(aA, vA); dot4(aB, vB);
            vA = nxA; vB = nxB;
        }
        dot4(aA, vA); dot4(aB, vB);
    }

    float c4[4];
#pragma unroll
    for (int j = 0; j < 4; j++) {
        float sel = (lane < 32) ? aB[j] : aA[j];
        float oth = __shfl_xor(sel, 32);
        c4[j] = ((lane < 32) ? aA[j] : aB[j]) + oth;
    }
#pragma unroll
    for (int m = 8; m <= 16; m <<= 1)
#pragma unroll
        for (int j = 0; j < 4; j++) c4[j] += __shfl_xor(c4[j], m);

    int node = (lane < 32) ? nA : nB;

    int2 sv = *(const int2*)(yb + (size_t)node * 64 + fo);
    dot4(c4, sv);

    float dvA = dinv[nA], dvB = dinv[nB];
    float dvS = (lane < 32) ? dvA : dvB;
    float4 b2v = *(const float4*)(b2 + 4 * f);
    float bbv[4] = {b2v.x, b2v.y, b2v.z, b2v.w};
    float4 o4;
    float* op = (float*)&o4;
#pragma unroll
    for (int j = 0; j < 4; j++)
        op[j] = fmaf(c4[j], dvS, bbv[j]);
    if ((lane & 31) < 8)
        *(float4*)(out + (size_t)node * CLS_F + f * 4) = o4;
}

extern "C" void kernel_launch(void* const* d_in, const int* in_sizes, int n_in,
                              void* d_out, int out_size, void* d_ws, size_t ws_size,
                              hipStream_t stream) {
    const float* x  = (const float*)d_in[0];
    const int*   ei = (const int*)d_in[1];
    // d_in[2] = edge_attr, unused by GCNConv
    const float* W1 = (const float*)d_in[3];
    const float* b1 = (const float*)d_in[4];
    const float* W2 = (const float*)d_in[5];
    const float* b2 = (const float*)d_in[6];
    float* out = (float*)d_out;

    const int* src = ei;
    const int* dst = ei + N_EDGES;

    char* ws = (char*)d_ws;
    size_t npad = ((size_t)N_NODES * 4 + 255) / 256 * 256;
    float* dinv = (float*)ws;
    int*   off  = (int*)(ws + npad);
    int*   endp = (int*)(ws + 2 * npad);
    int*   cursor = (int*)(ws + 3 * npad);            // 512 ints
    int*   csr  = (int*)(ws + 3 * npad + 2048);       // (NBKT+1)*CAPB ints (+slack bucket)
    char*  rbase = (char*)csr + (size_t)(NBKT + 1) * CAPB * 4;
    unsigned* bkt = (unsigned*)rbase;                 // NBKT*CAPB_RAW*4 = 8.4 MB, dead after sort
    unsigned short* y1h = (unsigned short*)rbase;     // (N+1)*64 fp16 = 12.8 MB, aliases bkt
    unsigned short* y2h = (unsigned short*)(rbase + (size_t)(N_NODES + 1) * HID_F * 2);  // 6.4 MB
    unsigned short* hbuf = (unsigned short*)((char*)y2h + (size_t)(N_NODES + 1) * CLS_F * 2); // 12.8 MB

    dim3 blk(256);
    init_cursor_kernel  <<<dim3(2), blk, 0, stream>>>(cursor);
    bucket_scatter_kernel<<<dim3(NBLK), blk, 0, stream>>>(src, dst, cursor, bkt);
    sort_bucket_kernel  <<<dim3(NBKT), blk, 0, stream>>>(cursor, bkt, csr, off, endp, dinv);
    xw1_kernel          <<<dim3((N_NODES + XBM - 1) / XBM), blk, 0, stream>>>(x, W1, dinv, y1h);
    gather1_kernel      <<<dim3(N_NODES / 8), blk, 0, stream>>>(off, endp, csr, y1h, dinv, b1, hbuf);
    y2_kernel           <<<dim3((N_NODES + YBM) / YBM), blk, 0, stream>>>(hbuf, W2, dinv, y2h);
    gather2_kernel      <<<dim3(N_NODES / 8), blk, 0, stream>>>(off, endp, csr, y2h, dinv, b2, out);
}

// Round 6
// 213.601 us; speedup vs baseline: 1.7654x; 1.0390x over previous
//
#include <hip/hip_runtime.h>
#include <hip/hip_fp16.h>

#define N_NODES 100000
#define N_EDGES 1600000
#define IN_F 128
#define HID_F 64
#define CLS_F 32

#define NBKT 512                 // buckets of 196 dst nodes each
#define BKT_NODES 196
#define NBLK 800                 // edge partition blocks (3.1 blocks/CU)
#define EPB 2000                 // edges per partition block (800*2000 = 1.6M exact)
#define CAPB_RAW 4096            // fixed raw staging region per bucket (mean 3136, +17 sigma)
#define CAPB 5120                // fixed padded csr region per bucket (mean ~3800, >20 sigma)
#define XW_BLOCKS 1563           // ceil(100001 / 64) node-GEMM blocks

typedef short s8v __attribute__((ext_vector_type(8)));
typedef float f4v __attribute__((ext_vector_type(4)));
typedef _Float16 h2v __attribute__((ext_vector_type(2)));

__device__ __forceinline__ unsigned short f2h(float f) {
    return __half_as_ushort(__float2half_rn(f));
}
__device__ __forceinline__ int packh2(float x, float y) {
    __half2 p = __floats2half2_rn(x, y);
    union { __half2 h; int i; } c; c.h = p; return c.i;
}

// acc[j] += dv * (float)h16[j]  -- compiles to v_fma_mix_f32 (1 instr/feat)
__device__ __forceinline__ void mix8(float* a, int4 v, float dv) {
    union { int4 i; __half h[8]; } c; c.i = v;
#pragma unroll
    for (int j = 0; j < 8; j++)
        a[j] = fmaf(__half2float(c.h[j]), dv, a[j]);
}

// gather2 accumulate: 1 fdot2 per feat (y2h rows pre-scaled, no per-edge dv)
__device__ __forceinline__ void dot4(float* a, int2 v) {
#if __has_builtin(__builtin_amdgcn_fdot2)
    union { int2 i; h2v h[2]; } c; c.i = v;
    const h2v E0 = {(_Float16)1.f, (_Float16)0.f};
    const h2v E1 = {(_Float16)0.f, (_Float16)1.f};
#pragma unroll
    for (int j = 0; j < 2; j++) {
        a[2 * j]     = __builtin_amdgcn_fdot2(c.h[j], E0, a[2 * j], false);
        a[2 * j + 1] = __builtin_amdgcn_fdot2(c.h[j], E1, a[2 * j + 1], false);
    }
#else
    union { int2 i; __half2 h[2]; } c; c.i = v;
#pragma unroll
    for (int j = 0; j < 2; j++) {
        float2 f = __half22float2(c.h[j]);
        a[2 * j] += f.x; a[2 * j + 1] += f.y;
    }
#endif
}

// ---------------------------------------------------------------------------
// CSR build v8. cursor[] holds per-bucket COUNTS (memset 0); staging regions
// are fixed at b*CAPB_RAW. One fused scatter kernel: LDS histogram -> one
// global atomicAdd per touched bucket -> LDS-cursor scatter.
// ---------------------------------------------------------------------------

__global__ __launch_bounds__(256) void bucket_scatter_kernel(
        const int* __restrict__ src, const int* __restrict__ dst,
        int* __restrict__ cursor, unsigned* __restrict__ bkt) {
    __shared__ int h[NBKT];
    __shared__ int base[NBKT];
    __shared__ int lcur[NBKT];
    __shared__ unsigned pkS[EPB];
    __shared__ short gS[EPB];
    int t = threadIdx.x;
    for (int i = t; i < NBKT; i += 256) { h[i] = 0; lcur[i] = 0; }
    __syncthreads();

    int e0 = blockIdx.x * EPB;
    for (int i = t; i < EPB; i += 256) {
        int e = e0 + i;
        int d = dst[e];
        int g = d / BKT_NODES;
        pkS[i] = ((unsigned)(d - g * BKT_NODES) << 17) | (unsigned)src[e];
        gS[i] = (short)g;
        atomicAdd(&h[g], 1);
    }
    __syncthreads();

    for (int g = t; g < NBKT; g += 256)
        if (h[g] > 0) base[g] = g * CAPB_RAW + atomicAdd(&cursor[g], h[g]);
    __syncthreads();

    for (int i = t; i < EPB; i += 256) {
        int g = gS[i];
        int p = base[g] + atomicAdd(&lcur[g], 1);
        bkt[p] = pkS[i];
    }
}

// ---------------------------------------------------------------------------
// Fused kernel: blocks [0, NBKT) = per-bucket counting sort (csr/off/endp/
// dinv); blocks [NBKT, NBKT+XW_BLOCKS) = y1 = x @ W1 via MFMA f16 (RAW, no
// dinv — gather1 folds dinv[src] per edge). Independent work, overlapped.
// Shared-LDS union (max 33.8 KB of the two paths).
// ---------------------------------------------------------------------------
#define XBM 64
#define SMEM_BYTES 33792

__device__ __forceinline__ void sort_body(char* smem, int b,
        const int* __restrict__ cursor, const unsigned* __restrict__ bkt,
        int* __restrict__ csr, int* __restrict__ off, int* __restrict__ endp,
        float* __restrict__ dinv) {
    int* hist  = (int*)smem;                    // 196
    int* loff  = hist + BKT_NODES;              // 196
    int* loffB = loff + BKT_NODES;              // 196
    int* wt    = loffB + BKT_NODES;             // 4
    int* csrS  = wt + 4;                        // 5120
    int t = threadIdx.x;
    int s0 = b * CAPB_RAW;
    int nE = cursor[b];                         // raw bucket size

    for (int i = t; i < BKT_NODES; i += 256) hist[i] = 0;
    __syncthreads();
    for (int i = t; i < nE; i += 256)
        atomicAdd(&hist[bkt[s0 + i] >> 17], 1);
    __syncthreads();

    // exclusive scan of PADDED per-node sizes (pad to multiple of 8)
    int h0 = 0, h1 = 0;
    if (t < 98) { h0 = hist[2 * t]; h1 = hist[2 * t + 1]; }
    int p0 = (h0 + 7) & ~7;
    int p1 = (h1 + 7) & ~7;
    int sum = p0 + p1;
    int lane = t & 63, w = t >> 6;
    int s = sum;
#pragma unroll
    for (int d = 1; d < 64; d <<= 1) {
        int u = __shfl_up(s, d);
        if (lane >= d) s += u;
    }
    if (lane == 63) wt[w] = s;
    __syncthreads();
    int wbase = 0;
    for (int i = 0; i < w; i++) wbase += wt[i];
    int excl = wbase + s - sum;
    if (t < 98) {
        loff[2 * t] = excl;         loffB[2 * t] = excl;
        loff[2 * t + 1] = excl + p0; loffB[2 * t + 1] = excl + p0;
    }
    __syncthreads();

    for (int j = t; j < BKT_NODES; j += 256) {
        int n = b * BKT_NODES + j;
        if (n < N_NODES) {
            int c = hist[j];
            int o = b * CAPB + loff[j];
            off[n] = o;
            endp[n] = o + ((c + 7) & ~7);          // padded length
            dinv[n] = rsqrtf((float)(c + 1));
        }
    }
    __syncthreads();

    // scatter into padded staging
    for (int i = t; i < nE; i += 256) {
        unsigned pk = bkt[s0 + i];
        int dl = (int)(pk >> 17);
        int p = atomicAdd(&loff[dl], 1);
        csrS[p] = (int)(pk & 0x1FFFFu);
    }
    __syncthreads();

    // fill pad slots with dummy node id (zero feature row, dinv=0)
    for (int j = t; j < BKT_NODES; j += 256) {
        int c = hist[j];
        int bse = loffB[j];
        int pe = bse + ((c + 7) & ~7);
        for (int p = bse + c; p < pe; p++) csrS[p] = N_NODES;
    }
    __syncthreads();

    int padTot = wt[0] + wt[1] + wt[2] + wt[3];
    for (int i = t; i < padTot; i += 256) csr[b * CAPB + i] = csrS[i];
}

__device__ __forceinline__ void xw1_body(char* smem, int xb_id,
        const float* __restrict__ x, const float* __restrict__ W1,
        unsigned short* __restrict__ y1h) {
    unsigned short* Wb = (unsigned short*)smem;            // 16 KB
    unsigned short (*xbuf)[IN_F + 8] =
        (unsigned short (*)[IN_F + 8])(smem + 16384);      // 17.4 KB
    int tid = threadIdx.x;

    for (int i = tid; i < IN_F * HID_F; i += 256) {
        int k = i >> 6, n = i & 63;
        int kc = k >> 5, kw = k & 31;
        int nt = n >> 4, nl = n & 15;
        int quad = kw >> 3, j = kw & 7;
        Wb[(((kc * 4 + nt) * 64) + quad * 16 + nl) * 8 + j] = f2h(W1[i]);
    }

    int nodeBase = xb_id * XBM;
    {
        int snl = tid >> 2;
        int sk0 = (tid & 3) * 32;
        int n = nodeBase + snl;
#pragma unroll
        for (int kk = 0; kk < 32; kk += 4) {
            float4 v = make_float4(0.f, 0.f, 0.f, 0.f);
            if (n < N_NODES) v = *(const float4*)(x + (size_t)n * IN_F + sk0 + kk);
            ushort4 o;
            o.x = f2h(v.x); o.y = f2h(v.y); o.z = f2h(v.z); o.w = f2h(v.w);
            *(ushort4*)(&xbuf[snl][sk0 + kk]) = o;
        }
    }
    __syncthreads();

    int wave = tid >> 6, lane = tid & 63;
    int quad = lane >> 4, l15 = lane & 15;
    int rowBase = wave * 16;

    f4v acc[4];
#pragma unroll
    for (int i = 0; i < 4; i++) acc[i] = (f4v){0.f, 0.f, 0.f, 0.f};

#pragma unroll
    for (int kc = 0; kc < 4; kc++) {
        s8v a = *(const s8v*)(&xbuf[rowBase + l15][kc * 32 + quad * 8]);
#pragma unroll
        for (int nt = 0; nt < 4; nt++) {
            s8v b = *(const s8v*)(&Wb[((kc * 4 + nt) * 64 + lane) * 8]);
            acc[nt] = __builtin_amdgcn_mfma_f32_16x16x32_f16(a, b, acc[nt], 0, 0, 0);
        }
    }

    int n0 = nodeBase + rowBase + quad * 4;
#pragma unroll
    for (int nt = 0; nt < 4; nt++) {
#pragma unroll
        for (int r = 0; r < 4; r++) {
            int n = n0 + r;
            if (n < N_NODES + 1)   // row N_NODES: zero-staged x -> writes 0
                y1h[(size_t)n * HID_F + nt * 16 + l15] = f2h(acc[nt][r]);
        }
    }
}

__global__ __launch_bounds__(256) void sort_xw1_kernel(
        const int* __restrict__ cursor, const unsigned* __restrict__ bkt,
        int* __restrict__ csr, int* __restrict__ off, int* __restrict__ endp,
        float* __restrict__ dinv, const float* __restrict__ x,
        const float* __restrict__ W1, unsigned short* __restrict__ y1h) {
    __shared__ __align__(16) char smem[SMEM_BYTES];
    int b = blockIdx.x;
    if (b < NBKT)
        sort_body(smem, b, cursor, bkt, csr, off, endp, dinv);
    else
        xw1_body(smem, b - NBKT, x, W1, y1h);
}

// ---------------------------------------------------------------------------
// gather1 v6: y1h rows are RAW xw (f16); dinv[src] folded per edge via
// v_fma_mix (f16 x f32 + f32). dv loads are 8-lane broadcasts, pipelined
// with the row prefetch; indices clamped to dummy N_NODES (dinv[N]=0, row 0).
// Output h = relu(dinv_d * agg + b1) fp16; W2 deferred to y2_kernel.
// ---------------------------------------------------------------------------
__global__ __launch_bounds__(256) void gather1_kernel(
        const int* __restrict__ off, const int* __restrict__ endp,
        const int* __restrict__ csr, const unsigned short* __restrict__ y1h,
        const float* __restrict__ dinv, const float* __restrict__ b1,
        unsigned short* __restrict__ hout) {
    int tid = threadIdx.x;
    int wv = __builtin_amdgcn_readfirstlane(tid >> 6);
    int wave = blockIdx.x * 4 + wv;
    int nA = wave * 2, nB = nA + 1;
    int lane = tid & 63;
    int f = lane & 7;
    int g = lane >> 3;
    int fo = f * 16;

    int offA = off[nA], offB = off[nB];          // uniform -> s_load
    int lenA = endp[nA] - offA, lenB = endp[nB] - offB;   // multiples of 8
    int lmax = max(lenA, lenB);
    const int* pA = csr + offA + g;
    const int* pB = csr + offB + g;
    const char* yb = (const char*)y1h;

    float aA[8], aB[8];
#pragma unroll
    for (int j = 0; j < 8; j++) { aA[j] = 0.f; aB[j] = 0.f; }

    if (lmax > 0) {
        int rA = pA[0], rB = pB[0];
        int iA = (lenA > 0) ? rA : N_NODES;
        int iB = (lenB > 0) ? rB : N_NODES;
        float dvA = dinv[iA], dvB = dinv[iB];
        int4 vA = *(const int4*)(yb + (size_t)iA * 128 + fo);
        int4 vB = *(const int4*)(yb + (size_t)iB * 128 + fo);
        int rA1 = pA[8], rB1 = pB[8];            // prefetch (csr has slack)
        for (int t = 8; t < lmax; t += 8) {
            int inA = (t < lenA) ? rA1 : N_NODES;
            int inB = (t < lenB) ? rB1 : N_NODES;
            float ndvA = dinv[inA], ndvB = dinv[inB];
            int4 nxA = *(const int4*)(yb + (size_t)inA * 128 + fo);
            int4 nxB = *(const int4*)(yb + (size_t)inB * 128 + fo);
            rA1 = pA[t + 8]; rB1 = pB[t + 8];    // prefetch (slack-covered)
            mix8(aA, vA, dvA); mix8(aB, vB, dvB);
            vA = nxA; vB = nxB; dvA = ndvA; dvB = ndvB;
        }
        mix8(aA, vA, dvA); mix8(aB, vB, dvB);
    }

    // merged butterfly: level 32 cross-select, then 16, 8
    float c8[8];
#pragma unroll
    for (int j = 0; j < 8; j++) {
        float sel = (lane < 32) ? aB[j] : aA[j];
        float oth = __shfl_xor(sel, 32);
        c8[j] = ((lane < 32) ? aA[j] : aB[j]) + oth;
    }
#pragma unroll
    for (int m = 8; m <= 16; m <<= 1)
#pragma unroll
        for (int j = 0; j < 8; j++) c8[j] += __shfl_xor(c8[j], m);

    int node = (lane < 32) ? nA : nB;
    float dvA = dinv[nA], dvB = dinv[nB];
    float dvS = (lane < 32) ? dvA : dvB;

    // self loop: dv_d * xw[d]
    int4 sv = *(const int4*)(yb + (size_t)node * 128 + fo);
    mix8(c8, sv, dvS);

    float4 bl = *(const float4*)(b1 + 8 * f);
    float4 bh4 = *(const float4*)(b1 + 8 * f + 4);
    float bb[8] = {bl.x, bl.y, bl.z, bl.w, bh4.x, bh4.y, bh4.z, bh4.w};
    float h[8];
#pragma unroll
    for (int j = 0; j < 8; j++)
        h[j] = fmaxf(fmaf(c8[j], dvS, bb[j]), 0.f);
    int4 H;
    H.x = packh2(h[0], h[1]); H.y = packh2(h[2], h[3]);
    H.z = packh2(h[4], h[5]); H.w = packh2(h[6], h[7]);
    if ((lane & 31) < 8)
        *(int4*)((char*)hout + (size_t)node * 128 + fo) = H;
}

// ---------------------------------------------------------------------------
// y2 = (h @ W2) * dinv via MFMA f16: 100K x 64 x 32. 64 nodes per block.
// Row N_NODES written as zeros (dummy target for gather2 padding).
// ---------------------------------------------------------------------------
#define YBM 64
__global__ __launch_bounds__(256) void y2_kernel(const unsigned short* __restrict__ h,
                                                 const float* __restrict__ W2,
                                                 const float* __restrict__ dinv,
                                                 unsigned short* __restrict__ y2h) {
    __shared__ __align__(16) unsigned short Wb[2 * 2 * 64 * 8];  // 4 KB
    __shared__ __align__(16) unsigned short hb[YBM][HID_F + 8];  // 9 KB
    int tid = threadIdx.x;

    for (int i = tid; i < HID_F * CLS_F; i += 256) {
        int k = i >> 5, n = i & 31;
        int kc = k >> 5, kw = k & 31;
        int nt = n >> 4, nl = n & 15;
        int quad = kw >> 3, j = kw & 7;
        Wb[(((kc * 2 + nt) * 64) + quad * 16 + nl) * 8 + j] = f2h(W2[i]);
    }

    int nodeBase = blockIdx.x * YBM;
    {
        int row = tid >> 2, sseg = tid & 3;
        int n = nodeBase + row;
        int4 v0 = {0, 0, 0, 0}, v1 = {0, 0, 0, 0};
        if (n < N_NODES) {
            const char* hp = (const char*)h + (size_t)n * 128 + sseg * 32;
            v0 = *(const int4*)hp;
            v1 = *(const int4*)(hp + 16);
        }
        *(int4*)(&hb[row][sseg * 16]) = v0;
        *(int4*)(&hb[row][sseg * 16 + 8]) = v1;
    }
    __syncthreads();

    int wave = tid >> 6, lane = tid & 63;
    int quad = lane >> 4, l15 = lane & 15;
    int rowBase = wave * 16;

    f4v acc[2];
#pragma unroll
    for (int i = 0; i < 2; i++) acc[i] = (f4v){0.f, 0.f, 0.f, 0.f};

#pragma unroll
    for (int kc = 0; kc < 2; kc++) {
        s8v a = *(const s8v*)(&hb[rowBase + l15][kc * 32 + quad * 8]);
#pragma unroll
        for (int nt = 0; nt < 2; nt++) {
            s8v b = *(const s8v*)(&Wb[((kc * 2 + nt) * 64 + lane) * 8]);
            acc[nt] = __builtin_amdgcn_mfma_f32_16x16x32_f16(a, b, acc[nt], 0, 0, 0);
        }
    }

    float dv[4];
    int n0 = nodeBase + rowBase + quad * 4;
#pragma unroll
    for (int r = 0; r < 4; r++)
        dv[r] = (n0 + r < N_NODES) ? dinv[n0 + r] : 0.f;
#pragma unroll
    for (int nt = 0; nt < 2; nt++) {
#pragma unroll
        for (int r = 0; r < 4; r++) {
            int n = n0 + r;
            if (n < N_NODES + 1)
                y2h[(size_t)n * CLS_F + nt * 16 + l15] = f2h(acc[nt][r] * dv[r]);
        }
    }
}

// ---------------------------------------------------------------------------
// gather2: rows are 64 B (32 fp16) -> dwordx2 per lane, 8 lanes per edge,
// 8 edges per wave-wide load. y2h pre-scaled (includes dinv[src]).
// out = (sum y2[nbr] + y2[self]) * dinv + b2, f32.
// ---------------------------------------------------------------------------
__global__ __launch_bounds__(256) void gather2_kernel(const int* __restrict__ off,
                                                      const int* __restrict__ endp,
                                                      const int* __restrict__ csr,
                                                      const unsigned short* __restrict__ y2h,
                                                      const float* __restrict__ dinv,
                                                      const float* __restrict__ b2,
                                                      float* __restrict__ out) {
    int tid = threadIdx.x;
    int wv = __builtin_amdgcn_readfirstlane(tid >> 6);
    int wave = blockIdx.x * 4 + wv;
    int nA = wave * 2, nB = nA + 1;
    int lane = tid & 63;
    int f = lane & 7;
    int g = lane >> 3;
    int fo = f * 8;

    int offA = off[nA], offB = off[nB];
    int lenA = endp[nA] - offA, lenB = endp[nB] - offB;
    int lmax = max(lenA, lenB);
    const int* pA = csr + offA + g;
    const int* pB = csr + offB + g;
    const char* yb = (const char*)y2h;

    float aA[4], aB[4];
#pragma unroll
    for (int j = 0; j < 4; j++) { aA[j] = 0.f; aB[j] = 0.f; }

    if (lmax > 0) {
        int rA = pA[0], rB = pB[0];
        int iA = (lenA > 0) ? rA : N_NODES;
        int iB = (lenB > 0) ? rB : N_NODES;
        int2 vA = *(const int2*)(yb + (size_t)iA * 64 + fo);
        int2 vB = *(const int2*)(yb + (size_t)iB * 64 + fo);
        int rA1 = pA[8], rB1 = pB[8];
        for (int t = 8; t < lmax; t += 8) {
            int inA = (t < lenA) ? rA1 : N_NODES;
            int inB = (t < lenB) ? rB1 : N_NODES;
            int2 nxA = *(const int2*)(yb + (size_t)inA * 64 + fo);
            int2 nxB = *(const int2*)(yb + (size_t)inB * 64 + fo);
            rA1 = pA[t + 8]; rB1 = pB[t + 8];
            dot4(aA, vA); dot4(aB, vB);
            vA = nxA; vB = nxB;
        }
        dot4(aA, vA); dot4(aB, vB);
    }

    float c4[4];
#pragma unroll
    for (int j = 0; j < 4; j++) {
        float sel = (lane < 32) ? aB[j] : aA[j];
        float oth = __shfl_xor(sel, 32);
        c4[j] = ((lane < 32) ? aA[j] : aB[j]) + oth;
    }
#pragma unroll
    for (int m = 8; m <= 16; m <<= 1)
#pragma unroll
        for (int j = 0; j < 4; j++) c4[j] += __shfl_xor(c4[j], m);

    int node = (lane < 32) ? nA : nB;

    int2 sv = *(const int2*)(yb + (size_t)node * 64 + fo);
    dot4(c4, sv);

    float dvA = dinv[nA], dvB = dinv[nB];
    float dvS = (lane < 32) ? dvA : dvB;
    float4 b2v = *(const float4*)(b2 + 4 * f);
    float bbv[4] = {b2v.x, b2v.y, b2v.z, b2v.w};
    float4 o4;
    float* op = (float*)&o4;
#pragma unroll
    for (int j = 0; j < 4; j++)
        op[j] = fmaf(c4[j], dvS, bbv[j]);
    if ((lane & 31) < 8)
        *(float4*)(out + (size_t)node * CLS_F + f * 4) = o4;
}

extern "C" void kernel_launch(void* const* d_in, const int* in_sizes, int n_in,
                              void* d_out, int out_size, void* d_ws, size_t ws_size,
                              hipStream_t stream) {
    const float* x  = (const float*)d_in[0];
    const int*   ei = (const int*)d_in[1];
    // d_in[2] = edge_attr, unused by GCNConv
    const float* W1 = (const float*)d_in[3];
    const float* b1 = (const float*)d_in[4];
    const float* W2 = (const float*)d_in[5];
    const float* b2 = (const float*)d_in[6];
    float* out = (float*)d_out;

    const int* src = ei;
    const int* dst = ei + N_EDGES;

    char* ws = (char*)d_ws;
    size_t npad = ((size_t)(N_NODES + 1) * 4 + 255) / 256 * 256;   // 400128
    float* dinv   = (float*)ws;                       // npad (incl dummy slot)
    int*   cursor = (int*)(ws + npad);                // 2048
    int*   off    = (int*)(ws + npad + 2048);
    int*   endp   = (int*)(ws + 2 * npad + 2048);
    int*   csr    = (int*)(ws + 3 * npad + 2048);     // (NBKT+1)*CAPB ints (+slack)
    char*  p = (char*)csr + (size_t)(NBKT + 1) * CAPB * 4;
    unsigned* bkt = (unsigned*)p;                     // 8.4 MB (live during sort_xw1)
    p += (size_t)NBKT * CAPB_RAW * 4;
    unsigned short* y1h = (unsigned short*)p;         // (N+1)*64 fp16 = 12.8 MB (no alias!)
    p += (size_t)(N_NODES + 1) * HID_F * 2;
    unsigned short* y2h = (unsigned short*)p;         // 6.4 MB
    p += (size_t)(N_NODES + 1) * CLS_F * 2;
    unsigned short* hbuf = (unsigned short*)p;        // 12.8 MB

    dim3 blk(256);
    // zero dinv (incl dummy slot N) + cursor counts, one memset
    hipMemsetAsync(ws, 0, npad + 2048, stream);
    bucket_scatter_kernel<<<dim3(NBLK), blk, 0, stream>>>(src, dst, cursor, bkt);
    sort_xw1_kernel<<<dim3(NBKT + XW_BLOCKS), blk, 0, stream>>>(
        cursor, bkt, csr, off, endp, dinv, x, W1, y1h);
    gather1_kernel<<<dim3(N_NODES / 8), blk, 0, stream>>>(off, endp, csr, y1h, dinv, b1, hbuf);
    y2_kernel<<<dim3((N_NODES + YBM) / YBM), blk, 0, stream>>>(hbuf, W2, dinv, y2h);
    gather2_kernel<<<dim3(N_NODES / 8), blk, 0, stream>>>(off, endp, csr, y2h, dinv, b2, out);
}